// Round 5
// baseline (418.765 us; speedup 1.0000x reference)
//
#include <hip/hip_runtime.h>
#include <stdint.h>

typedef unsigned short u16;
typedef __attribute__((ext_vector_type(8))) short short8;
typedef __attribute__((ext_vector_type(4))) float f32x4;

#define KGU  5120
#define HCOL 27648
#define NPD  2560
#define KD   27648
#define SPLITD 12
#define KCHD 2304            // 27648/12
#define PEL (256*2560)

#define BUF2 16384           // A bf16 8KB + B bf16 8KB
#define BOFF 8192

__device__ __forceinline__ void gl_lds16(const void* gp, void* lp) {
  __builtin_amdgcn_global_load_lds((const __attribute__((address_space(1))) uint32_t*)gp,
                                   (__attribute__((address_space(3))) uint32_t*)lp, 16, 0, 0);
}
__device__ __forceinline__ uint32_t f2bf(float x) {
  uint32_t b = __float_as_uint(x);
  return (b + 0x7fffu + ((b >> 16) & 1u)) >> 16;
}
__device__ __forceinline__ uint32_t pk2(float lo, float hi) { return f2bf(lo) | (f2bf(hi) << 16); }
__device__ __forceinline__ uint32_t cvtpk(float lo, float hi) {
  uint32_t r;
  asm("v_cvt_pk_bf16_f32 %0, %1, %2" : "=v"(r) : "v"(lo), "v"(hi));
  return r;
}
__device__ __forceinline__ float silu(float x) {
  return x * __builtin_amdgcn_rcpf(1.f + __expf(-x));
}

// ---------------- kernel 0: x fp32 -> bf16 ----------------
__global__ __launch_bounds__(256) void k_cvt(const float* __restrict__ X, u16* __restrict__ Xb) {
  int i = (blockIdx.x * 256 + threadIdx.x) * 8;
  float4 a = *(const float4*)(X + i);
  float4 b = *(const float4*)(X + i + 4);
  uint4 v;
  v.x = pk2(a.x, a.y); v.y = pk2(a.z, a.w); v.z = pk2(b.x, b.y); v.w = pk2(b.z, b.w);
  *(uint4*)(Xb + i) = v;
}

// ---------------- kernel 1: gate+up GEMM (BM=128 x 128 interleaved cols, BK=32) ----------------
// 256 thr / 4 waves (2M x 2N), wave tile 64x64, grid 432 (m fastest). LDS 2x16KB + consts.
// A: global_load_lds bf16. B: reg-staged fp32 -> cvt_pk -> bf16 LDS (T14 split).
__global__ __launch_bounds__(256, 2)
void k_gu(const u16* __restrict__ X,
          const float* __restrict__ Wg, const float* __restrict__ bg,
          const float* __restrict__ W1g, const float* __restrict__ b1g,
          const float* __restrict__ W2g, const float* __restrict__ b2g,
          const float* __restrict__ Wu, const float* __restrict__ bu,
          const float* __restrict__ W1u, const float* __restrict__ b1u,
          const float* __restrict__ W2u, const float* __restrict__ b2u,
          u16* __restrict__ H) {
  __shared__ __align__(16) char smem[2 * BUF2 + 1536];
  const int tid = threadIdx.x, lane = tid & 63, wid = tid >> 6;
  const int wm = wid >> 1, wn = wid & 1;
  const int s_ = lane & 15, quad = lane >> 4;
  const int m0 = (blockIdx.x & 1) * 128;
  const int j0 = (blockIdx.x >> 1) * 64;     // 64 j-pairs = 128 interleaved cols

  float4* mc4 = (float4*)(smem + 2 * BUF2);
  float*  mc1 = (float*)(smem + 2 * BUF2 + 1024);
  if (tid < 64) {
    int sel = tid >> 5, m = tid & 31;
    const float* w1 = (sel ? W1u : W1g) + m * 6;
    const float* b1 = sel ? b1u : b1g;
    const float* w2 = sel ? W2u : W2g;
    mc4[sel * 32 + m] = make_float4(w1[0] + w1[2] + w1[4], w1[1] + w1[3] + w1[5], b1[m], w2[m]);
    mc1[sel * 32 + m] = w2[32 + m];
  }

  // A: 8 chunks of 16 rows x 64B; wave owns chunks 2wid, 2wid+1. LDS row-major [r][slot].
  const int c2 = wid * 2;
  const u16* srcA0 = X + (size_t)(m0 + c2 * 16 + (lane >> 2)) * KGU + (lane & 3) * 8;
  const u16* srcA1 = srcA0 + (size_t)16 * KGU;
  const int dA0 = c2 * 1024, dA1 = dA0 + 1024;

  // B: thread -> row r (interleaved col), half h. 64B fp32 global -> 32B bf16 LDS.
  const int br = tid >> 1, bh = tid & 1;
  const float* srcB = ((br & 1) ? Wu : Wg) + (size_t)(j0 + (br >> 1)) * KGU + bh * 16;
  const int bwr = BOFF + br * 64 + bh * 32;

  const int aoff = (wm * 64 + s_) * 64 + quad * 16;          // + mi*1024
  const int boff = BOFF + (wn * 64 + s_) * 64 + quad * 16;   // + ni*1024

  f32x4 acc[4][4];
#pragma unroll
  for (int i = 0; i < 4; ++i)
#pragma unroll
    for (int j = 0; j < 4; ++j) acc[i][j] = (f32x4)0.f;

  float4 q0, q1, q2, q3;
  auto loadB = [&](int kt) {
    q0 = *(const float4*)(srcB + kt);
    q1 = *(const float4*)(srcB + kt + 4);
    q2 = *(const float4*)(srcB + kt + 8);
    q3 = *(const float4*)(srcB + kt + 12);
  };
  auto stageA = [&](int buf, int kt) {
    gl_lds16(srcA0 + kt, smem + buf + dA0);
    gl_lds16(srcA1 + kt, smem + buf + dA1);
  };
  auto writeB = [&](int buf) {
    uint4 v0, v1;
    v0.x = cvtpk(q0.x, q0.y); v0.y = cvtpk(q0.z, q0.w);
    v0.z = cvtpk(q1.x, q1.y); v0.w = cvtpk(q1.z, q1.w);
    v1.x = cvtpk(q2.x, q2.y); v1.y = cvtpk(q2.z, q2.w);
    v1.z = cvtpk(q3.x, q3.y); v1.w = cvtpk(q3.z, q3.w);
    *(uint4*)(smem + buf + bwr) = v0;
    *(uint4*)(smem + buf + bwr + 16) = v1;
  };
  auto compute = [&](int buf) {
    const char* base = smem + buf;
    short8 af[4], bf[4];
#pragma unroll
    for (int mi = 0; mi < 4; ++mi) af[mi] = *(const short8*)(base + aoff + mi * 1024);
#pragma unroll
    for (int ni = 0; ni < 4; ++ni) bf[ni] = *(const short8*)(base + boff + ni * 1024);
    __builtin_amdgcn_s_setprio(1);
#pragma unroll
    for (int mi = 0; mi < 4; ++mi)
#pragma unroll
      for (int ni = 0; ni < 4; ++ni)
        acc[mi][ni] = __builtin_amdgcn_mfma_f32_16x16x32_bf16(af[mi], bf[ni], acc[mi][ni], 0, 0, 0);
    __builtin_amdgcn_s_setprio(0);
  };

  // prologue: tile 0
  loadB(0); stageA(0, 0);
  asm volatile("s_waitcnt vmcnt(2)" ::: "memory");
  writeB(0);
  asm volatile("s_waitcnt vmcnt(0) lgkmcnt(0)" ::: "memory");
  __builtin_amdgcn_sched_barrier(0);
  __builtin_amdgcn_s_barrier();
  int cur = 0;
#pragma unroll 1
  for (int t = 0; t < 159; ++t) {            // 160 K-tiles
    const int kt = (t + 1) * 32;
    const int bo = cur << 14, bn = bo ^ BUF2;
    loadB(kt);
    stageA(bn, kt);
    __builtin_amdgcn_sched_barrier(0);
    compute(bo);
    __builtin_amdgcn_sched_barrier(0);
    asm volatile("s_waitcnt vmcnt(2)" ::: "memory");
    writeB(bn);
    asm volatile("s_waitcnt vmcnt(0) lgkmcnt(0)" ::: "memory");
    __builtin_amdgcn_sched_barrier(0);
    __builtin_amdgcn_s_barrier();
    cur ^= 1;
  }
  compute(cur << 14);

  // ---- fused epilogue: qrun per lane (gate even / up odd), shfl pair, silu*up ----
  const int sel = lane & 1;
  const float b2v0 = sel ? b2u[0] : b2g[0];
  const float b2v1 = sel ? b2u[1] : b2g[1];
  const float4* mcs = mc4 + sel * 32;
  const float*  mcw = mc1 + sel * 32;
#pragma unroll
  for (int ni = 0; ni < 4; ++ni) {
    const int c = wn * 64 + ni * 16 + s_;
    const int j = j0 + (c >> 1);
    const float bp = sel ? bu[j] : bg[j];
#pragma unroll
    for (int mi = 0; mi < 4; ++mi) {
      float sv[4], cv[4], o0[4], o1[4];
#pragma unroll
      for (int e = 0; e < 4; ++e) {
        float p = acc[mi][ni][e] + bp;
        sv[e] = __sinf(p); cv[e] = __cosf(p);
        o0[e] = b2v0; o1[e] = b2v1;
      }
#pragma unroll 4
      for (int m = 0; m < 32; ++m) {
        float4 k4 = mcs[m]; float w2b = mcw[m];
#pragma unroll
        for (int e = 0; e < 4; ++e) {
          float hh = fmaxf(fmaf(sv[e], k4.x, fmaf(cv[e], k4.y, k4.z)), 0.f);
          o0[e] = fmaf(hh, k4.w, o0[e]);
          o1[e] = fmaf(hh, w2b, o1[e]);
        }
      }
#pragma unroll
      for (int e = 0; e < 4; ++e) {
        float t0 = __shfl_xor(o0[e], 1);
        float t1 = __shfl_xor(o1[e], 1);
        float g0 = sel ? t0 : o0[e];
        float u0 = sel ? o0[e] : t0;
        float g1 = sel ? t1 : o1[e];
        float u1 = sel ? o1[e] : t1;
        float h0 = silu(g0) * u0, h1 = silu(g1) * u1;
        if (!sel) {
          const int row = m0 + wm * 64 + mi * 16 + quad * 4 + e;
          *(uint32_t*)&H[(size_t)row * HCOL + 2 * j] = pk2(h0, h1);
        }
      }
    }
  }
}

// ---------------- kernel 2: down GEMM (BM=128 x BN=128, BK=32, splitK=12) ----------------
__global__ __launch_bounds__(256, 2)
void k_down(const u16* __restrict__ Hb, const float* __restrict__ Wd, float* __restrict__ P2) {
  __shared__ __align__(16) char smem[2 * BUF2];
  const int tid = threadIdx.x, lane = tid & 63, wid = tid >> 6;
  const int wm = wid >> 1, wn = wid & 1;
  const int s_ = lane & 15, quad = lane >> 4;
  const int m0 = (blockIdx.x & 1) * 128;
  const int n0 = (blockIdx.x >> 1) * 128;
  const int kc = blockIdx.y * KCHD;

  const int c2 = wid * 2;
  const u16* srcA0 = Hb + (size_t)(m0 + c2 * 16 + (lane >> 2)) * KD + kc + (lane & 3) * 8;
  const u16* srcA1 = srcA0 + (size_t)16 * KD;
  const int dA0 = c2 * 1024, dA1 = dA0 + 1024;

  const int br = tid >> 1, bh = tid & 1;
  const float* srcB = Wd + (size_t)(n0 + br) * KD + kc + bh * 16;
  const int bwr = BOFF + br * 64 + bh * 32;

  const int aoff = (wm * 64 + s_) * 64 + quad * 16;
  const int boff = BOFF + (wn * 64 + s_) * 64 + quad * 16;

  f32x4 acc[4][4];
#pragma unroll
  for (int i = 0; i < 4; ++i)
#pragma unroll
    for (int j = 0; j < 4; ++j) acc[i][j] = (f32x4)0.f;

  float4 q0, q1, q2, q3;
  auto loadB = [&](int kt) {
    q0 = *(const float4*)(srcB + kt);
    q1 = *(const float4*)(srcB + kt + 4);
    q2 = *(const float4*)(srcB + kt + 8);
    q3 = *(const float4*)(srcB + kt + 12);
  };
  auto stageA = [&](int buf, int kt) {
    gl_lds16(srcA0 + kt, smem + buf + dA0);
    gl_lds16(srcA1 + kt, smem + buf + dA1);
  };
  auto writeB = [&](int buf) {
    uint4 v0, v1;
    v0.x = cvtpk(q0.x, q0.y); v0.y = cvtpk(q0.z, q0.w);
    v0.z = cvtpk(q1.x, q1.y); v0.w = cvtpk(q1.z, q1.w);
    v1.x = cvtpk(q2.x, q2.y); v1.y = cvtpk(q2.z, q2.w);
    v1.z = cvtpk(q3.x, q3.y); v1.w = cvtpk(q3.z, q3.w);
    *(uint4*)(smem + buf + bwr) = v0;
    *(uint4*)(smem + buf + bwr + 16) = v1;
  };
  auto compute = [&](int buf) {
    const char* base = smem + buf;
    short8 af[4], bf[4];
#pragma unroll
    for (int mi = 0; mi < 4; ++mi) af[mi] = *(const short8*)(base + aoff + mi * 1024);
#pragma unroll
    for (int ni = 0; ni < 4; ++ni) bf[ni] = *(const short8*)(base + boff + ni * 1024);
    __builtin_amdgcn_s_setprio(1);
#pragma unroll
    for (int mi = 0; mi < 4; ++mi)
#pragma unroll
      for (int ni = 0; ni < 4; ++ni)
        acc[mi][ni] = __builtin_amdgcn_mfma_f32_16x16x32_bf16(af[mi], bf[ni], acc[mi][ni], 0, 0, 0);
    __builtin_amdgcn_s_setprio(0);
  };

  loadB(0); stageA(0, 0);
  asm volatile("s_waitcnt vmcnt(2)" ::: "memory");
  writeB(0);
  asm volatile("s_waitcnt vmcnt(0) lgkmcnt(0)" ::: "memory");
  __builtin_amdgcn_sched_barrier(0);
  __builtin_amdgcn_s_barrier();
  int cur = 0;
#pragma unroll 1
  for (int t = 0; t < 71; ++t) {               // 72 K-tiles
    const int kt = (t + 1) * 32;
    const int bo = cur << 14, bn = bo ^ BUF2;
    loadB(kt);
    stageA(bn, kt);
    __builtin_amdgcn_sched_barrier(0);
    compute(bo);
    __builtin_amdgcn_sched_barrier(0);
    asm volatile("s_waitcnt vmcnt(2)" ::: "memory");
    writeB(bn);
    asm volatile("s_waitcnt vmcnt(0) lgkmcnt(0)" ::: "memory");
    __builtin_amdgcn_sched_barrier(0);
    __builtin_amdgcn_s_barrier();
    cur ^= 1;
  }
  compute(cur << 14);

  const size_t pb = (size_t)blockIdx.y * PEL;
#pragma unroll
  for (int mi = 0; mi < 4; ++mi) {
    int mrow = m0 + wm * 64 + mi * 16 + (quad << 2);
#pragma unroll
    for (int ni = 0; ni < 4; ++ni) {
      int n = n0 + wn * 64 + ni * 16 + s_;
#pragma unroll
      for (int e = 0; e < 4; ++e)
        P2[pb + (size_t)(mrow + e) * NPD + n] = acc[mi][ni][e];
    }
  }
}

// ---------------- kernel 3: reduce partials + QRUN-d epilogue -> out fp32 ----------------
__global__ __launch_bounds__(256) void k_fin(const float* __restrict__ P2, const float* __restrict__ bd,
    const float* __restrict__ W1d, const float* __restrict__ b1d, const float* __restrict__ W2d,
    const float* __restrict__ b2d, float* __restrict__ out) {
  __shared__ float4 mc0[32];
  __shared__ float mc1[32];
  const int tid = threadIdx.x;
  if (tid < 32) {
    const float* w = W1d + tid * 6;
    mc0[tid] = make_float4(w[0] + w[2] + w[4], w[1] + w[3] + w[5], b1d[tid], W2d[tid]);
    mc1[tid] = W2d[32 + tid];
  }
  __syncthreads();
  const int idx = blockIdx.x * 256 + tid;
  const int m = idx / NPD, j = idx - m * NPD;
  float p = bd[j];
#pragma unroll
  for (int sk = 0; sk < SPLITD; ++sk) p += P2[(size_t)sk * PEL + idx];
  float s = __sinf(p), c = __cosf(p);
  float o0 = b2d[0], o1 = b2d[1];
#pragma unroll 4
  for (int mm = 0; mm < 32; ++mm) {
    float4 k = mc0[mm];
    float hh = fmaxf(fmaf(s, k.x, fmaf(c, k.y, k.z)), 0.f);
    o0 = fmaf(hh, k.w, o0);
    o1 = fmaf(hh, mc1[mm], o1);
  }
  *(float2*)&out[(size_t)m * 5120 + 2 * j] = make_float2(o0, o1);
}

extern "C" void kernel_launch(void* const* d_in, const int* in_sizes, int n_in,
                              void* d_out, int out_size, void* d_ws, size_t ws_size,
                              hipStream_t stream) {
  const float* x   = (const float*)d_in[0];
  const float* Wg  = (const float*)d_in[1];
  const float* bg  = (const float*)d_in[2];
  const float* W1g = (const float*)d_in[3];
  const float* b1g = (const float*)d_in[4];
  const float* W2g = (const float*)d_in[5];
  const float* b2g = (const float*)d_in[6];
  const float* Wu  = (const float*)d_in[7];
  const float* bu  = (const float*)d_in[8];
  const float* W1u = (const float*)d_in[9];
  const float* b1u = (const float*)d_in[10];
  const float* W2u = (const float*)d_in[11];
  const float* b2u = (const float*)d_in[12];
  const float* Wd  = (const float*)d_in[13];
  const float* bd  = (const float*)d_in[14];
  const float* W1d = (const float*)d_in[15];
  const float* b1d = (const float*)d_in[16];
  const float* W2d = (const float*)d_in[17];
  const float* b2d = (const float*)d_in[18];
  char* ws = (char*)d_ws;
  u16*  xb = (u16*)ws;                    // 2,621,440 B
  u16*  hb = (u16*)(ws + 2621440);        // 14,155,776 B (ends 16,777,216)
  float* P2 = (float*)(ws + 16777216);    // 12 x 655360 x 4 = 31,457,280 B
  if (ws_size < 48234496u) return;

  k_cvt<<<dim3(640), dim3(256), 0, stream>>>(x, xb);
  k_gu<<<dim3(432), dim3(256), 0, stream>>>(xb, Wg, bg, W1g, b1g, W2g, b2g,
                                            Wu, bu, W1u, b1u, W2u, b2u, hb);
  k_down<<<dim3(40, SPLITD), dim3(256), 0, stream>>>(hb, Wd, P2);
  k_fin<<<dim3(2560), dim3(256), 0, stream>>>(P2, bd, W1d, b1d, W2d, b2d, (float*)d_out);
}